// Round 2
// baseline (790.358 us; speedup 1.0000x reference)
//
#include <hip/hip_runtime.h>
#include <hip/hip_bf16.h>
#include <stdint.h>

#define B 16
#define NM 56
#define G 1681
#define GP 1684          // padded row stride for f32 state buffers
#define LAYERS 10
#define KS 8             // k-split for ATb partial reduction
#define KCH 211          // ceil(G/KS)

typedef __hip_bfloat16 bf16;

// dtype-polymorphic loads/stores (all math in f32)
__device__ __forceinline__ float ldv(const float* p, size_t i) { return p[i]; }
__device__ __forceinline__ float ldv(const bf16*  p, size_t i) { return __bfloat162float(p[i]); }
__device__ __forceinline__ void  stv(float* p, size_t i, float v) { p[i] = v; }
__device__ __forceinline__ void  stv(bf16*  p, size_t i, float v) { p[i] = __float2bfloat16(v); }

// ---------------------------------------------------------------------------
// Detect input dtype from lambda_step[0] (== 1.0 by construction):
//   f32 1.0 -> 0x3F800000 ; two bf16 1.0 -> 0x3F803F80
__global__ void detect_kernel(const uint32_t* lam_bits, int* flag)
{
    if (threadIdx.x == 0) flag[0] = (lam_bits[0] == 0x3F800000u) ? 1 : 0;
}

// ---------------------------------------------------------------------------
// DAS[b,g] = Re( sum_i conj(w[b,i,g]) * sum_j CSM[b,i,j]*w[b,j,g] ) * s^2/NM^2
template <typename T>
__device__ void das_body(const T* Cre, const T* Cim, const T* Wre, const T* Wim,
                         const T* wk_w, float2* csm, float (*pr)[64],
                         float* __restrict__ DAS)
{
    const int b = blockIdx.y;
    const int t = threadIdx.x;
    for (int idx = t; idx < NM * NM; idx += 256)
        csm[idx] = make_float2(ldv(Cre, (size_t)b * NM * NM + idx),
                               ldv(Cim, (size_t)b * NM * NM + idx));
    __syncthreads();

    const int tg = t & 63;
    const int tc = t >> 6;
    const int g = blockIdx.x * 64 + tg;
    float acc = 0.f;
    if (g < G) {
        const size_t wbase = (size_t)b * NM * G + g;
        for (int i = tc * 14; i < tc * 14 + 14; ++i) {
            float tre = 0.f, tim = 0.f;
            for (int j = 0; j < NM; ++j) {
                float2 c = csm[i * NM + j];
                float wrj = ldv(Wre, wbase + (size_t)j * G);
                float wij = ldv(Wim, wbase + (size_t)j * G);
                tre += c.x * wrj - c.y * wij;
                tim += c.x * wij + c.y * wrj;
            }
            float wri = ldv(Wre, wbase + (size_t)i * G);
            float wii = ldv(Wim, wbase + (size_t)i * G);
            acc += wri * tre + wii * tim;
        }
    }
    pr[tc][tg] = acc;
    __syncthreads();
    if (tc == 0 && g < G) {
        float s = ldv(wk_w, 0);
        float total = pr[0][tg] + pr[1][tg] + pr[2][tg] + pr[3][tg];
        DAS[b * G + g] = total * s * s * (1.0f / (NM * NM));
    }
}

__global__ __launch_bounds__(256) void das_kernel(
    const void* Cre, const void* Cim, const void* Wre, const void* Wim,
    const void* wk_w, const int* __restrict__ flag, float* __restrict__ DAS)
{
    __shared__ float2 csm[NM * NM];
    __shared__ float pr[4][64];
    if (*flag)
        das_body((const float*)Cre, (const float*)Cim, (const float*)Wre,
                 (const float*)Wim, (const float*)wk_w, csm, pr, DAS);
    else
        das_body((const bf16*)Cre, (const bf16*)Cim, (const bf16*)Wre,
                 (const bf16*)Wim, (const bf16*)wk_w, csm, pr, DAS);
}

// ---------------------------------------------------------------------------
// partial[ks][b,g] = sum_{k in chunk ks} A_K[b,k,g] * DAS[b,k]
template <typename T>
__device__ void atb_body(const T* A, const float* __restrict__ DAS,
                         float* __restrict__ partial)
{
    const int gt = blockIdx.x;
    const int ks = blockIdx.y;
    const int b  = blockIdx.z;
    const int g = gt * 256 + threadIdx.x;
    if (g >= G) return;
    const int k0 = ks * KCH;
    const int k1 = min(k0 + KCH, G);
    const size_t base = (size_t)b * G * G + g;
    const float* d = DAS + b * G;
    float acc = 0.f;
    for (int k = k0; k < k1; ++k)
        acc += ldv(A, base + (size_t)k * G) * d[k];
    partial[((size_t)ks * B + b) * G + g] = acc;
}

__global__ __launch_bounds__(256) void atb_partial_kernel(
    const void* A, const float* __restrict__ DAS,
    const int* __restrict__ flag, float* __restrict__ partial)
{
    if (*flag) atb_body((const float*)A, DAS, partial);
    else       atb_body((const bf16*)A,  DAS, partial);
}

// ---------------------------------------------------------------------------
// Layer 0 specialization (y0 = x0 = 0): reduce partials -> ATb, x1, y1.
template <typename T>
__device__ void layer0_body(const float* __restrict__ partial, const T* L_K,
                            const T* lam_s, const T* w_rho, const T* b_rho,
                            float* __restrict__ ATb, float* __restrict__ x1,
                            float* __restrict__ y1)
{
    int idx = blockIdx.x * 256 + threadIdx.x;   // over B*GP
    if (idx >= B * GP) return;
    int b = idx / GP, g = idx % GP;
    if (g >= G) { ATb[idx] = 0.f; x1[idx] = 0.f; y1[idx] = 0.f; return; }
    float a = 0.f;
    for (int s = 0; s < KS; ++s) a += partial[((size_t)s * B + b) * G + g];
    float invL = 1.f / ldv(L_K, b);
    float lam = ldv(lam_s, 0);
    float x = fmaxf(invL * lam * a, 0.f);
    float wr = ldv(w_rho, 0), br = ldv(b_rho, 0);
    ATb[idx] = a;
    x1[idx] = x;
    y1[idx] = (wr + br) * x;   // x - xold = x since xold = 0
}

__global__ __launch_bounds__(256) void layer0_kernel(
    const float* __restrict__ partial, const void* L_K, const void* lam_s,
    const void* w_rho, const void* b_rho, const int* __restrict__ flag,
    float* __restrict__ ATb, float* __restrict__ x1, float* __restrict__ y1)
{
    if (*flag)
        layer0_body(partial, (const float*)L_K, (const float*)lam_s,
                    (const float*)w_rho, (const float*)b_rho, ATb, x1, y1);
    else
        layer0_body(partial, (const bf16*)L_K, (const bf16*)lam_s,
                    (const bf16*)w_rho, (const bf16*)b_rho, ATb, x1, y1);
}

// ---------------------------------------------------------------------------
// One FISTA layer: wave-per-row matvec over ATA_K (lanes stride k, coalesced).
template <typename T>
__device__ void iter_body(const T* ATA, const float* __restrict__ y_old,
                          const float* __restrict__ x_old,
                          const float* __restrict__ ATb,
                          const T* L_K, const T* lam_s, const T* ys_s,
                          const T* w_rho, const T* b_rho, int layer,
                          float* __restrict__ x_new, float* __restrict__ y_new)
{
    const int lane = threadIdx.x & 63;
    const int row = blockIdx.x * 4 + (threadIdx.x >> 6);   // exactly B*G rows
    const int b = row / G;
    const int g = row - b * G;
    const size_t abase = ((size_t)b * G + g) * G;
    const float* yo = y_old + b * GP;

    float acc = 0.f;
    int k = lane;
    #pragma unroll 4
    for (int i = 0; i < 26; ++i, k += 64)      // 26*64 = 1664 full chunks
        acc += ldv(ATA, abase + k) * yo[k];
    if (k < G)                                  // tail: lanes 0..16
        acc += ldv(ATA, abase + k) * yo[k];

    #pragma unroll
    for (int off = 32; off > 0; off >>= 1)
        acc += __shfl_down(acc, off, 64);

    if (lane == 0) {
        float invL = 1.f / ldv(L_K, b);
        float lam = ldv(lam_s, layer);
        float ys  = ldv(ys_s, layer);
        float r = ys * yo[g] - invL * lam * acc + invL * lam * ATb[b * GP + g];
        float x = fmaxf(r, 0.f);
        float wr = ldv(w_rho, 0), br = ldv(b_rho, 0);
        x_new[b * GP + g] = x;
        y_new[b * GP + g] = wr * x + br * (x - x_old[b * GP + g]);
    }
}

__global__ __launch_bounds__(256) void iter_kernel(
    const void* ATA, const float* __restrict__ y_old,
    const float* __restrict__ x_old, const float* __restrict__ ATb,
    const void* L_K, const void* lam_s, const void* ys_s,
    const void* w_rho, const void* b_rho, int layer,
    const int* __restrict__ flag,
    float* __restrict__ x_new, float* __restrict__ y_new)
{
    if (*flag)
        iter_body((const float*)ATA, y_old, x_old, ATb, (const float*)L_K,
                  (const float*)lam_s, (const float*)ys_s, (const float*)w_rho,
                  (const float*)b_rho, layer, x_new, y_new);
    else
        iter_body((const bf16*)ATA, y_old, x_old, ATb, (const bf16*)L_K,
                  (const bf16*)lam_s, (const bf16*)ys_s, (const bf16*)w_rho,
                  (const bf16*)b_rho, layer, x_new, y_new);
}

// ---------------------------------------------------------------------------
// out[b,g] = relu(w1*(sum_k x10[b,k]*W[g,k] + bias[g]) + w2*x10[b,g])
template <typename T>
__device__ void final_body(const float* __restrict__ x10, const T* W,
                           const T* bias, const T* w1p, const T* w2p,
                           float (*xs)[256], float (*red)[B], T* out)
{
    const int g = blockIdx.x;
    const int t = threadIdx.x;
    float acc[B];
    #pragma unroll
    for (int b = 0; b < B; ++b) acc[b] = 0.f;
    const size_t wbase = (size_t)g * G;

    for (int k0 = 0; k0 < G; k0 += 256) {
        const int k = k0 + t;
        #pragma unroll
        for (int b = 0; b < B; ++b)
            xs[b][t] = (k < G) ? x10[b * GP + k] : 0.f;
        __syncthreads();
        float w = (k < G) ? ldv(W, wbase + k) : 0.f;
        #pragma unroll
        for (int b = 0; b < B; ++b) acc[b] += xs[b][t] * w;
        __syncthreads();
    }

    #pragma unroll
    for (int b = 0; b < B; ++b) {
        float v = acc[b];
        #pragma unroll
        for (int off = 32; off > 0; off >>= 1)
            v += __shfl_down(v, off, 64);
        if ((t & 63) == 0) red[t >> 6][b] = v;
    }
    __syncthreads();
    if (t < B) {
        float z = red[0][t] + red[1][t] + red[2][t] + red[3][t] + ldv(bias, g);
        float w1 = ldv(w1p, 0), w2 = ldv(w2p, 0);
        float o = w1 * z + w2 * x10[t * GP + g];
        stv(out, (size_t)t * G + g, fmaxf(o, 0.f));
    }
}

__global__ __launch_bounds__(256) void final_kernel(
    const float* __restrict__ x10, const void* W, const void* bias,
    const void* w1p, const void* w2p, const int* __restrict__ flag, void* out)
{
    __shared__ float xs[B][256];
    __shared__ float red[4][B];
    if (*flag)
        final_body(x10, (const float*)W, (const float*)bias, (const float*)w1p,
                   (const float*)w2p, xs, red, (float*)out);
    else
        final_body(x10, (const bf16*)W, (const bf16*)bias, (const bf16*)w1p,
                   (const bf16*)w2p, xs, red, (bf16*)out);
}

// ---------------------------------------------------------------------------
extern "C" void kernel_launch(void* const* d_in, const int* in_sizes, int n_in,
                              void* d_out, int out_size, void* d_ws, size_t ws_size,
                              hipStream_t stream)
{
    const void* CSM_re = d_in[0];
    const void* CSM_im = d_in[1];
    const void* wk_re  = d_in[2];
    const void* wk_im  = d_in[3];
    const void* A_K    = d_in[4];
    const void* ATA_K  = d_in[5];
    const void* L_K    = d_in[6];
    const void* lam_s  = d_in[7];
    const void* ys_s   = d_in[8];
    const void* wk_w   = d_in[9];
    const void* w_rho  = d_in[10];
    const void* b_rho  = d_in[11];
    const void* lin_W  = d_in[12];
    const void* lin_b  = d_in[13];
    const void* w1     = d_in[14];
    const void* w2     = d_in[15];

    int*   flag    = (int*)d_ws;
    float* ws      = (float*)((char*)d_ws + 16);
    float* DAS     = ws;                    // B*G
    float* partial = DAS + B * G;           // KS*B*G
    float* ATb     = partial + KS * B * G;  // B*GP
    float* xb0     = ATb + B * GP;          // B*GP
    float* xb1     = xb0 + B * GP;
    float* yb0     = xb1 + B * GP;
    float* yb1     = yb0 + B * GP;          // total ~1.51 MB of ws

    detect_kernel<<<1, 64, 0, stream>>>((const uint32_t*)lam_s, flag);
    das_kernel<<<dim3(27, 16), 256, 0, stream>>>(CSM_re, CSM_im, wk_re, wk_im,
                                                 wk_w, flag, DAS);
    atb_partial_kernel<<<dim3(7, KS, B), 256, 0, stream>>>(A_K, DAS, flag, partial);
    layer0_kernel<<<(B * GP + 255) / 256, 256, 0, stream>>>(partial, L_K, lam_s,
                                                            w_rho, b_rho, flag,
                                                            ATb, xb0, yb0);
    float* xs_[2] = {xb0, xb1};
    float* ys_[2] = {yb0, yb1};
    int cur = 0;
    for (int i = 1; i < LAYERS; ++i) {
        int dst = 1 - cur;
        iter_kernel<<<(B * G) / 4, 256, 0, stream>>>(ATA_K, ys_[cur], xs_[cur], ATb,
                                                     L_K, lam_s, ys_s, w_rho, b_rho,
                                                     i, flag, xs_[dst], ys_[dst]);
        cur = dst;
    }
    final_kernel<<<G, 256, 0, stream>>>(xs_[cur], lin_W, lin_b, w1, w2, flag, d_out);
}

// Round 3
// 681.283 us; speedup vs baseline: 1.1601x; 1.1601x over previous
//
#include <hip/hip_runtime.h>
#include <hip/hip_bf16.h>
#include <stdint.h>

#define B 16
#define NM 56
#define G 1681
#define GP 1684          // padded row stride for f32 state buffers
#define LAYERS 10
#define KS 8             // k-split for ATb partial reduction
#define KCH 211          // ceil(G/KS)

typedef __hip_bfloat16 bf16;

// dtype-polymorphic loads/stores (all math in f32)
__device__ __forceinline__ float ldv(const float* p, size_t i) { return p[i]; }
__device__ __forceinline__ float ldv(const bf16*  p, size_t i) { return __bfloat162float(p[i]); }
__device__ __forceinline__ void  stv(float* p, size_t i, float v) { p[i] = v; }
__device__ __forceinline__ void  stv(bf16*  p, size_t i, float v) { p[i] = __float2bfloat16(v); }

// ---------------------------------------------------------------------------
// Detect input dtype from lambda_step[0] (== 1.0 by construction):
//   f32 1.0 -> 0x3F800000 ; two bf16 1.0 -> 0x3F803F80
__global__ void detect_kernel(const uint32_t* lam_bits, int* flag)
{
    if (threadIdx.x == 0) flag[0] = (lam_bits[0] == 0x3F800000u) ? 1 : 0;
}

// ---------------------------------------------------------------------------
// DAS[b,g] = Re( sum_i conj(w[b,i,g]) * sum_j CSM[b,i,j]*w[b,j,g] ) * s^2/NM^2
// CSM and the w-tile (56 x 64 g's) staged in LDS; compute is register-blocked
// 14 i's per thread (4 i-chunks x 64 g-lanes per 256-thread block).
template <typename T>
__device__ void das_body(const T* Cre, const T* Cim, const T* Wre, const T* Wim,
                         const T* wk_w, float2* csm, float2* wlds, float (*pr)[64],
                         float* __restrict__ DAS)
{
    const int b = blockIdx.y;
    const int t = threadIdx.x;
    for (int idx = t; idx < NM * NM; idx += 256)
        csm[idx] = make_float2(ldv(Cre, (size_t)b * NM * NM + idx),
                               ldv(Cim, (size_t)b * NM * NM + idx));
    const int gbase = blockIdx.x * 64;
    for (int idx = t; idx < NM * 64; idx += 256) {
        int j = idx >> 6, g0 = idx & 63;
        int g = gbase + g0;
        float re = 0.f, im = 0.f;
        if (g < G) {
            size_t off = (size_t)b * NM * G + (size_t)j * G + g;
            re = ldv(Wre, off);
            im = ldv(Wim, off);
        }
        wlds[idx] = make_float2(re, im);
    }
    __syncthreads();

    const int tg = t & 63;
    const int tc = t >> 6;
    const int i0 = tc * 14;
    float tre[14], tim[14];
    #pragma unroll
    for (int i = 0; i < 14; ++i) { tre[i] = 0.f; tim[i] = 0.f; }

    for (int j = 0; j < NM; ++j) {
        float2 w = wlds[j * 64 + tg];
        #pragma unroll
        for (int i = 0; i < 14; ++i) {
            float2 c = csm[(i0 + i) * NM + j];   // broadcast across lanes
            tre[i] += c.x * w.x - c.y * w.y;
            tim[i] += c.x * w.y + c.y * w.x;
        }
    }
    float acc = 0.f;
    #pragma unroll
    for (int i = 0; i < 14; ++i) {
        float2 wi = wlds[(i0 + i) * 64 + tg];
        acc += wi.x * tre[i] + wi.y * tim[i];
    }
    pr[tc][tg] = acc;
    __syncthreads();
    if (tc == 0) {
        int g = gbase + tg;
        if (g < G) {
            float s = ldv(wk_w, 0);
            float total = pr[0][tg] + pr[1][tg] + pr[2][tg] + pr[3][tg];
            DAS[b * G + g] = total * s * s * (1.0f / (NM * NM));
        }
    }
}

__global__ __launch_bounds__(256) void das_kernel(
    const void* Cre, const void* Cim, const void* Wre, const void* Wim,
    const void* wk_w, const int* __restrict__ flag, float* __restrict__ DAS)
{
    __shared__ float2 csm[NM * NM];
    __shared__ float2 wlds[NM * 64];
    __shared__ float pr[4][64];
    if (*flag)
        das_body((const float*)Cre, (const float*)Cim, (const float*)Wre,
                 (const float*)Wim, (const float*)wk_w, csm, wlds, pr, DAS);
    else
        das_body((const bf16*)Cre, (const bf16*)Cim, (const bf16*)Wre,
                 (const bf16*)Wim, (const bf16*)wk_w, csm, wlds, pr, DAS);
}

// ---------------------------------------------------------------------------
// partial[ks][b,g] = sum_{k in chunk ks} A_K[b,k,g] * DAS[b,k]
// 8 independent accumulators -> 8+ outstanding loads per wave (latency fix).
template <typename T>
__device__ void atb_body(const T* A, const float* __restrict__ DAS,
                         float* __restrict__ partial)
{
    const int gt = blockIdx.x;
    const int ks = blockIdx.y;
    const int b  = blockIdx.z;
    const int g = gt * 256 + threadIdx.x;
    if (g >= G) return;
    const int k0 = ks * KCH;
    const int k1 = min(k0 + KCH, G);
    const size_t base = (size_t)b * G * G + g;
    const float* d = DAS + b * G;
    float a0=0.f,a1=0.f,a2=0.f,a3=0.f,a4=0.f,a5=0.f,a6=0.f,a7=0.f;
    int k = k0;
    for (; k + 8 <= k1; k += 8) {
        a0 += ldv(A, base + (size_t)(k+0) * G) * d[k+0];
        a1 += ldv(A, base + (size_t)(k+1) * G) * d[k+1];
        a2 += ldv(A, base + (size_t)(k+2) * G) * d[k+2];
        a3 += ldv(A, base + (size_t)(k+3) * G) * d[k+3];
        a4 += ldv(A, base + (size_t)(k+4) * G) * d[k+4];
        a5 += ldv(A, base + (size_t)(k+5) * G) * d[k+5];
        a6 += ldv(A, base + (size_t)(k+6) * G) * d[k+6];
        a7 += ldv(A, base + (size_t)(k+7) * G) * d[k+7];
    }
    for (; k < k1; ++k)
        a0 += ldv(A, base + (size_t)k * G) * d[k];
    partial[((size_t)ks * B + b) * G + g] =
        ((a0 + a1) + (a2 + a3)) + ((a4 + a5) + (a6 + a7));
}

__global__ __launch_bounds__(256) void atb_partial_kernel(
    const void* A, const float* __restrict__ DAS,
    const int* __restrict__ flag, float* __restrict__ partial)
{
    if (*flag) atb_body((const float*)A, DAS, partial);
    else       atb_body((const bf16*)A,  DAS, partial);
}

// ---------------------------------------------------------------------------
// Layer 0 specialization (y0 = x0 = 0): reduce partials -> ATb, x1, y1.
template <typename T>
__device__ void layer0_body(const float* __restrict__ partial, const T* L_K,
                            const T* lam_s, const T* w_rho, const T* b_rho,
                            float* __restrict__ ATb, float* __restrict__ x1,
                            float* __restrict__ y1)
{
    int idx = blockIdx.x * 256 + threadIdx.x;   // over B*GP
    if (idx >= B * GP) return;
    int b = idx / GP, g = idx % GP;
    if (g >= G) { ATb[idx] = 0.f; x1[idx] = 0.f; y1[idx] = 0.f; return; }
    float a = 0.f;
    #pragma unroll
    for (int s = 0; s < KS; ++s) a += partial[((size_t)s * B + b) * G + g];
    float invL = 1.f / ldv(L_K, b);
    float lam = ldv(lam_s, 0);
    float x = fmaxf(invL * lam * a, 0.f);
    float wr = ldv(w_rho, 0), br = ldv(b_rho, 0);
    ATb[idx] = a;
    x1[idx] = x;
    y1[idx] = (wr + br) * x;   // x - xold = x since xold = 0
}

__global__ __launch_bounds__(256) void layer0_kernel(
    const float* __restrict__ partial, const void* L_K, const void* lam_s,
    const void* w_rho, const void* b_rho, const int* __restrict__ flag,
    float* __restrict__ ATb, float* __restrict__ x1, float* __restrict__ y1)
{
    if (*flag)
        layer0_body(partial, (const float*)L_K, (const float*)lam_s,
                    (const float*)w_rho, (const float*)b_rho, ATb, x1, y1);
    else
        layer0_body(partial, (const bf16*)L_K, (const bf16*)lam_s,
                    (const bf16*)w_rho, (const bf16*)b_rho, ATb, x1, y1);
}

// ---------------------------------------------------------------------------
// One FISTA layer: wave-per-row matvec. Fully unrolled k-loop with 8
// accumulator chains -> ~26 outstanding loads per wave; single base register
// + immediate offsets (i*128 B <= 3200 < 4095).
template <typename T>
__device__ void iter_body(const T* ATA, const float* __restrict__ y_old,
                          const float* __restrict__ x_old,
                          const float* __restrict__ ATb,
                          const T* L_K, const T* lam_s, const T* ys_s,
                          const T* w_rho, const T* b_rho, int layer,
                          float* __restrict__ x_new, float* __restrict__ y_new)
{
    const int lane = threadIdx.x & 63;
    const int row = blockIdx.x * 4 + (threadIdx.x >> 6);   // exactly B*G rows
    const int b = row / G;
    const int g = row - b * G;
    const size_t abase = ((size_t)b * G + g) * G + lane;
    const float* yo = y_old + b * GP;

    float acc[8];
    #pragma unroll
    for (int i = 0; i < 8; ++i) acc[i] = 0.f;

    #pragma unroll
    for (int i = 0; i < 26; ++i) {            // 26*64 = 1664 full chunks
        int k = i * 64 + lane;
        acc[i & 7] += ldv(ATA, abase + i * 64) * yo[k];
    }
    {
        int k = 1664 + lane;                   // tail: lanes 0..16
        if (k < G) acc[0] += ldv(ATA, abase + 1664) * yo[k];
    }
    float s = ((acc[0] + acc[1]) + (acc[2] + acc[3])) +
              ((acc[4] + acc[5]) + (acc[6] + acc[7]));

    #pragma unroll
    for (int off = 32; off > 0; off >>= 1)
        s += __shfl_down(s, off, 64);

    if (lane == 0) {
        float invL = 1.f / ldv(L_K, b);
        float lam = ldv(lam_s, layer);
        float ys  = ldv(ys_s, layer);
        float r = ys * yo[g] - invL * lam * s + invL * lam * ATb[b * GP + g];
        float x = fmaxf(r, 0.f);
        float wr = ldv(w_rho, 0), br = ldv(b_rho, 0);
        x_new[b * GP + g] = x;
        y_new[b * GP + g] = wr * x + br * (x - x_old[b * GP + g]);
    }
}

__global__ __launch_bounds__(256) void iter_kernel(
    const void* ATA, const float* __restrict__ y_old,
    const float* __restrict__ x_old, const float* __restrict__ ATb,
    const void* L_K, const void* lam_s, const void* ys_s,
    const void* w_rho, const void* b_rho, int layer,
    const int* __restrict__ flag,
    float* __restrict__ x_new, float* __restrict__ y_new)
{
    if (*flag)
        iter_body((const float*)ATA, y_old, x_old, ATb, (const float*)L_K,
                  (const float*)lam_s, (const float*)ys_s, (const float*)w_rho,
                  (const float*)b_rho, layer, x_new, y_new);
    else
        iter_body((const bf16*)ATA, y_old, x_old, ATb, (const bf16*)L_K,
                  (const bf16*)lam_s, (const bf16*)ys_s, (const bf16*)w_rho,
                  (const bf16*)b_rho, layer, x_new, y_new);
}

// ---------------------------------------------------------------------------
// out[b,g] = relu(w1*(sum_k x10[b,k]*W[g,k] + bias[g]) + w2*x10[b,g])
template <typename T>
__device__ void final_body(const float* __restrict__ x10, const T* W,
                           const T* bias, const T* w1p, const T* w2p,
                           float (*xs)[256], float (*red)[B], T* out)
{
    const int g = blockIdx.x;
    const int t = threadIdx.x;
    float acc[B];
    #pragma unroll
    for (int b = 0; b < B; ++b) acc[b] = 0.f;
    const size_t wbase = (size_t)g * G;

    for (int k0 = 0; k0 < G; k0 += 256) {
        const int k = k0 + t;
        #pragma unroll
        for (int b = 0; b < B; ++b)
            xs[b][t] = (k < G) ? x10[b * GP + k] : 0.f;
        __syncthreads();
        float w = (k < G) ? ldv(W, wbase + k) : 0.f;
        #pragma unroll
        for (int b = 0; b < B; ++b) acc[b] += xs[b][t] * w;
        __syncthreads();
    }

    #pragma unroll
    for (int b = 0; b < B; ++b) {
        float v = acc[b];
        #pragma unroll
        for (int off = 32; off > 0; off >>= 1)
            v += __shfl_down(v, off, 64);
        if ((t & 63) == 0) red[t >> 6][b] = v;
    }
    __syncthreads();
    if (t < B) {
        float z = red[0][t] + red[1][t] + red[2][t] + red[3][t] + ldv(bias, g);
        float w1 = ldv(w1p, 0), w2 = ldv(w2p, 0);
        float o = w1 * z + w2 * x10[t * GP + g];
        stv(out, (size_t)t * G + g, fmaxf(o, 0.f));
    }
}

__global__ __launch_bounds__(256) void final_kernel(
    const float* __restrict__ x10, const void* W, const void* bias,
    const void* w1p, const void* w2p, const int* __restrict__ flag, void* out)
{
    __shared__ float xs[B][256];
    __shared__ float red[4][B];
    if (*flag)
        final_body(x10, (const float*)W, (const float*)bias, (const float*)w1p,
                   (const float*)w2p, xs, red, (float*)out);
    else
        final_body(x10, (const bf16*)W, (const bf16*)bias, (const bf16*)w1p,
                   (const bf16*)w2p, xs, red, (bf16*)out);
}

// ---------------------------------------------------------------------------
extern "C" void kernel_launch(void* const* d_in, const int* in_sizes, int n_in,
                              void* d_out, int out_size, void* d_ws, size_t ws_size,
                              hipStream_t stream)
{
    const void* CSM_re = d_in[0];
    const void* CSM_im = d_in[1];
    const void* wk_re  = d_in[2];
    const void* wk_im  = d_in[3];
    const void* A_K    = d_in[4];
    const void* ATA_K  = d_in[5];
    const void* L_K    = d_in[6];
    const void* lam_s  = d_in[7];
    const void* ys_s   = d_in[8];
    const void* wk_w   = d_in[9];
    const void* w_rho  = d_in[10];
    const void* b_rho  = d_in[11];
    const void* lin_W  = d_in[12];
    const void* lin_b  = d_in[13];
    const void* w1     = d_in[14];
    const void* w2     = d_in[15];

    int*   flag    = (int*)d_ws;
    float* ws      = (float*)((char*)d_ws + 16);
    float* DAS     = ws;                    // B*G
    float* partial = DAS + B * G;           // KS*B*G
    float* ATb     = partial + KS * B * G;  // B*GP
    float* xb0     = ATb + B * GP;          // B*GP
    float* xb1     = xb0 + B * GP;
    float* yb0     = xb1 + B * GP;
    float* yb1     = yb0 + B * GP;          // total ~1.51 MB of ws

    detect_kernel<<<1, 64, 0, stream>>>((const uint32_t*)lam_s, flag);
    das_kernel<<<dim3(27, 16), 256, 0, stream>>>(CSM_re, CSM_im, wk_re, wk_im,
                                                 wk_w, flag, DAS);
    atb_partial_kernel<<<dim3(7, KS, B), 256, 0, stream>>>(A_K, DAS, flag, partial);
    layer0_kernel<<<(B * GP + 255) / 256, 256, 0, stream>>>(partial, L_K, lam_s,
                                                            w_rho, b_rho, flag,
                                                            ATb, xb0, yb0);
    float* xs_[2] = {xb0, xb1};
    float* ys_[2] = {yb0, yb1};
    int cur = 0;
    for (int i = 1; i < LAYERS; ++i) {
        int dst = 1 - cur;
        iter_kernel<<<(B * G) / 4, 256, 0, stream>>>(ATA_K, ys_[cur], xs_[cur], ATb,
                                                     L_K, lam_s, ys_s, w_rho, b_rho,
                                                     i, flag, xs_[dst], ys_[dst]);
        cur = dst;
    }
    final_kernel<<<G, 256, 0, stream>>>(xs_[cur], lin_W, lin_b, w1, w2, flag, d_out);
}